// Round 6
// baseline (6717.150 us; speedup 1.0000x reference)
//
#include <hip/hip_runtime.h>
#include <stdint.h>

#define NN 10000
#define NE 160000
// C=64, M=9, H=8, D=8, RH=64, WN=192

struct BF16 { unsigned short v; };

__device__ __forceinline__ float cvt(float x) { return x; }
__device__ __forceinline__ float cvt(BF16 x) {
    union { unsigned int i; float f; } u; u.i = ((unsigned int)x.v) << 16; return u.f;
}
__device__ __forceinline__ unsigned short f2b_us(float f) {
    union { float f; unsigned int i; } v; v.f = f;
    unsigned int x = v.i;
    unsigned int lsb = (x >> 16) & 1u;
    x += 0x7fffu + lsb;
    return (unsigned short)(x >> 16);
}
__device__ __forceinline__ float rlane(float v, int l) {
    return __uint_as_float((unsigned int)__builtin_amdgcn_readlane(__float_as_uint(v), l));
}
__device__ __forceinline__ float sigm(float x) { return 1.0f / (1.0f + __expf(-x)); }
__device__ __forceinline__ int clampi(int v, int hi) { return (unsigned)v >= (unsigned)hi ? 0 : v; }

// out-store helpers (dtype-dependent)
__device__ __forceinline__ void stOut(float* p, size_t i, float v) { p[i] = v; }
__device__ __forceinline__ void stOut(unsigned short* p, size_t i, float v) { p[i] = f2b_us(v); }

// ---------------- K0: zero cnt + csr, init flag ----------------
__global__ void k0_zero(int* __restrict__ cnt, int* __restrict__ csr, int* __restrict__ flag) {
    int i = blockIdx.x * blockDim.x + threadIdx.x;
    if (i == 0) *flag = 1;            // default: bf16; probe clears to 0 on f32 evidence
    if (i < NN) cnt[i] = 0;
    if (i < NE) csr[i] = 0;
}

// ---------------- KP: dtype probe ----------------
// bf16-encoded normal data never has exponent field 0xFF; f32 storage read as u16
// exposes mantissa halves whose bits are ~uniform -> ~32 expected 0xFF hits in 16384.
__global__ void kprobe(const unsigned short* __restrict__ x, int* __restrict__ flag) {
    int bad = 0;
    for (int i = threadIdx.x; i < 16384; i += blockDim.x) {
        unsigned e = (x[i] >> 7) & 0xFFu;
        bad += (e == 0xFFu);
    }
    if (bad > 0) atomicExch(flag, 0);  // f32 world
}

// ---------------- K1 body: node feats ----------------
template<typename T>
__device__ void k1_body(const T* x, const T* Ws, const T* bs, const T* Wd,
                        _Float16* fs, _Float16* fd)
{
    int lane = threadIdx.x;
    float ws[64], wd[64];
#pragma unroll
    for (int i = 0; i < 64; i++) { ws[i] = cvt(Ws[i * 64 + lane]); wd[i] = cvt(Wd[i * 64 + lane]); }
    float bsl = cvt(bs[lane]);
    const int ROWS = NN * 9;
    for (int r = blockIdx.x; r < ROWS; r += gridDim.x) {
        float xv = cvt(x[(size_t)r * 64 + lane]);
        float a0 = 0, a1 = 0, a2 = 0, a3 = 0, d0 = 0, d1 = 0, d2 = 0, d3 = 0;
#pragma unroll
        for (int i = 0; i < 64; i += 4) {
            float x0 = rlane(xv, i), x1 = rlane(xv, i + 1), x2 = rlane(xv, i + 2), x3 = rlane(xv, i + 3);
            a0 = fmaf(x0, ws[i], a0);     a1 = fmaf(x1, ws[i + 1], a1);
            a2 = fmaf(x2, ws[i + 2], a2); a3 = fmaf(x3, ws[i + 3], a3);
            d0 = fmaf(x0, wd[i], d0);     d1 = fmaf(x1, wd[i + 1], d1);
            d2 = fmaf(x2, wd[i + 2], d2); d3 = fmaf(x3, wd[i + 3], d3);
        }
        float as = a0 + a1 + a2 + a3;
        if ((r % 9) == 0) as += bsl;
        fs[(size_t)r * 64 + lane] = (_Float16)as;
        fd[(size_t)r * 64 + lane] = (_Float16)(d0 + d1 + d2 + d3);
    }
}

__global__ __launch_bounds__(64) void k1_feats(
    const void* x, const void* Ws, const void* bs, const void* Wd,
    _Float16* fs, _Float16* fd, const int* flag)
{
    if (*flag) k1_body((const BF16*)x, (const BF16*)Ws, (const BF16*)bs, (const BF16*)Wd, fs, fd);
    else       k1_body((const float*)x, (const float*)Ws, (const float*)bs, (const float*)Wd, fs, fd);
}

// ---------------- K2: CSR build ----------------
__global__ void k2a_count(const int* __restrict__ dst, int* __restrict__ cnt) {
    for (int e = blockIdx.x * blockDim.x + threadIdx.x; e < NE; e += gridDim.x * blockDim.x)
        atomicAdd(&cnt[clampi(dst[e], NN)], 1);
}

__global__ __launch_bounds__(1024) void k2b_scan(const int* __restrict__ cnt,
                                                 int* __restrict__ off, int* __restrict__ cur) {
    __shared__ int part[1024];
    int t = threadIdx.x;
    int base = t * 10;
    int loc[10]; int s = 0;
#pragma unroll
    for (int k = 0; k < 10; k++) { int i = base + k; int v = (i < NN) ? cnt[i] : 0; loc[k] = v; s += v; }
    part[t] = s; __syncthreads();
    for (int o = 1; o < 1024; o <<= 1) {
        int v = (t >= o) ? part[t - o] : 0;
        __syncthreads();
        part[t] += v;
        __syncthreads();
    }
    int run = (t == 0) ? 0 : part[t - 1];
#pragma unroll
    for (int k = 0; k < 10; k++) {
        int i = base + k;
        if (i < NN) { off[i] = run; cur[i] = run; run += loc[k]; }
    }
    if (t == 1023) off[NN] = part[1023];
}

__global__ void k2c_fill(const int* __restrict__ dst, int* __restrict__ cur, int* __restrict__ csr) {
    for (int e = blockIdx.x * blockDim.x + threadIdx.x; e < NE; e += gridDim.x * blockDim.x) {
        int d = clampi(dst[e], NN);
        int p = atomicAdd(&cur[d], 1);
        if ((unsigned)p < (unsigned)NE) csr[p] = e;
    }
}

// ---------------- K3 body: radial hidden h = silu(LN(s@W1+b1)*g+b) ----------------
template<typename T>
__device__ void k3_body(const T* es, const T* W1, const T* b1, const T* g, const T* bln,
                        _Float16* hout)
{
    int lane = threadIdx.x;
    float w1[64];
#pragma unroll
    for (int i = 0; i < 64; i++) w1[i] = cvt(W1[i * 64 + lane]);
    float b1l = cvt(b1[lane]), gl = cvt(g[lane]), bl = cvt(bln[lane]);
    for (int e = blockIdx.x; e < NE; e += gridDim.x) {
        float sv = cvt(es[(size_t)e * 64 + lane]);
        float h0 = 0, h1 = 0, h2 = 0, h3 = 0;
#pragma unroll
        for (int i = 0; i < 64; i += 4) {
            h0 = fmaf(rlane(sv, i), w1[i], h0);
            h1 = fmaf(rlane(sv, i + 1), w1[i + 1], h1);
            h2 = fmaf(rlane(sv, i + 2), w1[i + 2], h2);
            h3 = fmaf(rlane(sv, i + 3), w1[i + 3], h3);
        }
        float h = h0 + h1 + h2 + h3 + b1l;
        float s1 = h, s2 = h * h;
#pragma unroll
        for (int o = 32; o >= 1; o >>= 1) { s1 += __shfl_xor(s1, o, 64); s2 += __shfl_xor(s2, o, 64); }
        float mu = s1 * (1.0f / 64.0f);
        float var = fmaxf(s2 * (1.0f / 64.0f) - mu * mu, 0.0f);
        h = (h - mu) * rsqrtf(var + 1e-5f) * gl + bl;
        h = h * sigm(h);
        hout[(size_t)e * 64 + lane] = (_Float16)h;
    }
}

__global__ __launch_bounds__(64) void k3_h(
    const void* es, const void* W1, const void* b1, const void* g, const void* bln,
    _Float16* hout, const int* flag)
{
    if (*flag) k3_body((const BF16*)es, (const BF16*)W1, (const BF16*)b1, (const BF16*)g, (const BF16*)bln, hout);
    else       k3_body((const float*)es, (const float*)W1, (const float*)b1, (const float*)g, (const float*)bln, hout);
}

// ---------------- K4 body: alpha logits (wl0 recomputed from h) ----------------
template<typename T>
__device__ void k4_body(const T* ea, const _Float16* fs, const _Float16* fd,
                        const _Float16* hb, const T* W2, const T* roff,
                        const T* Wa, const T* ba, const T* adot,
                        const int* esrc, const int* edst, float* alpha)
{
    int lane = threadIdx.x;
    float w2a[64], wa[64];
#pragma unroll
    for (int i = 0; i < 64; i++) {
        w2a[i] = cvt(W2[i * 192 + lane]);
        wa[i]  = cvt(Wa[i * 64 + lane]);
    }
    float o0 = cvt(roff[lane]);
    float bal = cvt(ba[lane]), adl = cvt(adot[lane]);
    for (int e = blockIdx.x; e < NE; e += gridDim.x) {
        int sn = clampi(esrc[e], NN), dn = clampi(edst[e], NN);
        float hv = (float)hb[(size_t)e * 64 + lane];
        float wl0 = o0;
#pragma unroll
        for (int q = 0; q < 64; q++) wl0 = fmaf(rlane(hv, q), w2a[q], wl0);
        float ea0 = cvt(ea[(size_t)e * 9]);
        float m0 = ((float)fs[(size_t)sn * 576 + lane] + (float)fd[(size_t)dn * 576 + lane]) * ea0 * wl0;
        float a0 = 0, a1 = 0, a2 = 0, a3 = 0;
#pragma unroll
        for (int i = 0; i < 64; i += 4) {
            a0 = fmaf(rlane(m0, i), wa[i], a0);
            a1 = fmaf(rlane(m0, i + 1), wa[i + 1], a1);
            a2 = fmaf(rlane(m0, i + 2), wa[i + 2], a2);
            a3 = fmaf(rlane(m0, i + 3), wa[i + 3], a3);
        }
        float aw = a0 + a1 + a2 + a3 + bal;
        float f = aw * (0.2f + 0.8f * sigm(aw));   // smooth_lrelu
        float p = f * adl;
        p += __shfl_xor(p, 1, 64);
        p += __shfl_xor(p, 2, 64);
        p += __shfl_xor(p, 4, 64);
        if ((lane & 7) == 0) alpha[(size_t)e * 8 + (lane >> 3)] = p;
    }
}

__global__ __launch_bounds__(64) void k4_alpha(
    const void* ea, const _Float16* fs, const _Float16* fd, const _Float16* hb,
    const void* W2, const void* roff, const void* Wa, const void* ba, const void* adot,
    const int* esrc, const int* edst, float* alpha, const int* flag)
{
    if (*flag) k4_body((const BF16*)ea, fs, fd, hb, (const BF16*)W2, (const BF16*)roff,
                       (const BF16*)Wa, (const BF16*)ba, (const BF16*)adot, esrc, edst, alpha);
    else       k4_body((const float*)ea, fs, fd, hb, (const float*)W2, (const float*)roff,
                       (const float*)Wa, (const float*)ba, (const float*)adot, esrc, edst, alpha);
}

// ---------------- K5: segment softmax per (node, head), in place ----------------
__global__ void k5_softmax(const int* __restrict__ off, const int* __restrict__ csr,
                           float* __restrict__ alpha) {
    int t = blockIdx.x * blockDim.x + threadIdx.x;
    if (t >= NN * 8) return;
    int n = t >> 3, h = t & 7;
    int b = off[n], en = off[n + 1];
    float mx = -3.4e38f;
    for (int i = b; i < en; i++)
        mx = fmaxf(mx, alpha[(size_t)clampi(csr[i], NE) * 8 + h]);
    float s = 0.f;
    for (int i = b; i < en; i++) {
        size_t ix = (size_t)clampi(csr[i], NE) * 8 + h;
        float ex = __expf(alpha[ix] - mx);
        s += ex;
        alpha[ix] = ex;
    }
    float inv = 1.0f / (s + 1e-16f);
    for (int i = b; i < en; i++) {
        size_t ix = (size_t)clampi(csr[i], NE) * 8 + h;
        alpha[ix] *= inv;
    }
}

// ---------------- K6 body: fused wl recompute + msg + value GEMV + gate + cp_tp + gather ----------------
template<typename T>
__device__ void k6_body(const int* off, const int* csr, const int* esrc,
                        const T* ea, const _Float16* fs, const _Float16* fd,
                        const _Float16* hb, const T* W2, const T* roff,
                        const T* Wv, const T* bv, const float* alpha, _Float16* nsum)
{
    int lane = threadIdx.x;
    float w2a[64], w2b[64], w2c[64], wv[64], wg[64];
#pragma unroll
    for (int i = 0; i < 64; i++) {
        w2a[i] = cvt(W2[i * 192 + lane]);
        w2b[i] = cvt(W2[i * 192 + 64 + lane]);
        w2c[i] = cvt(W2[i * 192 + 128 + lane]);
        wv[i]  = cvt(Wv[i * 128 + lane]);
        wg[i]  = cvt(Wv[i * 128 + 64 + lane]);
    }
    float o0 = cvt(roff[lane]), o1 = cvt(roff[64 + lane]), o2 = cvt(roff[128 + lane]);
    float bvl = cvt(bv[lane]), bgl = cvt(bv[64 + lane]);
    __shared__ __align__(16) float msg_s[9 * 64];
    for (int n = blockIdx.x; n < NN; n += gridDim.x) {
        float acc[9];
#pragma unroll
        for (int m = 0; m < 9; m++) acc[m] = 0.f;
        int b = off[n], en = off[n + 1];
        size_t db = (size_t)n * 576 + lane;
        for (int i = b; i < en; i++) {
            int e = clampi(csr[i], NE);
            int sn = clampi(esrc[e], NN);
            size_t sb = (size_t)sn * 576 + lane;
            float hv = (float)hb[(size_t)e * 64 + lane];
            float wl0 = o0, wl1 = o1, wl2 = o2;
#pragma unroll
            for (int q = 0; q < 64; q++) {
                float hq = rlane(hv, q);
                wl0 = fmaf(hq, w2a[q], wl0);
                wl1 = fmaf(hq, w2b[q], wl1);
                wl2 = fmaf(hq, w2c[q], wl2);
            }
            float cw[9];
#pragma unroll
            for (int m = 0; m < 9; m++) {
                float wl = (m == 0) ? wl0 : ((m < 4) ? wl1 : wl2);
                cw[m] = cvt(ea[(size_t)e * 9 + m]) * wl;
            }
#pragma unroll
            for (int m = 0; m < 9; m++)
                msg_s[m * 64 + lane] = ((float)fs[sb + m * 64] + (float)fd[db + m * 64]) * cw[m];
            __syncthreads();
            float aw = alpha[(size_t)e * 8 + (lane >> 3)];
            float va0 = 0, va1 = 0, va2 = 0, va3 = 0, ga0 = 0, ga1 = 0, ga2 = 0, ga3 = 0;
#pragma unroll
            for (int c = 0; c < 64; c += 4) {
                float4 mv = *(const float4*)&msg_s[c];
                va0 = fmaf(mv.x, wv[c], va0);     va1 = fmaf(mv.y, wv[c + 1], va1);
                va2 = fmaf(mv.z, wv[c + 2], va2); va3 = fmaf(mv.w, wv[c + 3], va3);
                ga0 = fmaf(mv.x, wg[c], ga0);     ga1 = fmaf(mv.y, wg[c + 1], ga1);
                ga2 = fmaf(mv.z, wg[c + 2], ga2); ga3 = fmaf(mv.w, wg[c + 3], ga3);
            }
            float v0 = va0 + va1 + va2 + va3 + bvl;
            float gt = sigm(ga0 + ga1 + ga2 + ga3 + bgl);
            acc[0] = fmaf(v0 * sigm(v0) * cw[0], aw, acc[0]);
#pragma unroll
            for (int m = 1; m < 9; m++) {
                float q0 = 0, q1 = 0, q2 = 0, q3 = 0;
#pragma unroll
                for (int c = 0; c < 64; c += 4) {
                    float4 mv = *(const float4*)&msg_s[m * 64 + c];
                    q0 = fmaf(mv.x, wv[c], q0);     q1 = fmaf(mv.y, wv[c + 1], q1);
                    q2 = fmaf(mv.z, wv[c + 2], q2); q3 = fmaf(mv.w, wv[c + 3], q3);
                }
                acc[m] = fmaf((q0 + q1 + q2 + q3) * gt * cw[m], aw, acc[m]);
            }
            __syncthreads();
        }
#pragma unroll
        for (int m = 0; m < 9; m++)
            nsum[(size_t)n * 576 + m * 64 + lane] = (_Float16)acc[m];
    }
}

__global__ __launch_bounds__(64, 1) void k6_fused(
    const int* off, const int* csr, const int* esrc,
    const void* ea, const _Float16* fs, const _Float16* fd, const _Float16* hb,
    const void* W2, const void* roff, const void* Wv, const void* bv,
    const float* alpha, _Float16* nsum, const int* flag)
{
    if (*flag) k6_body<BF16>(off, csr, esrc, (const BF16*)ea, fs, fd, hb,
                             (const BF16*)W2, (const BF16*)roff,
                             (const BF16*)Wv, (const BF16*)bv, alpha, nsum);
    else       k6_body<float>(off, csr, esrc, (const float*)ea, fs, fd, hb,
                              (const float*)W2, (const float*)roff,
                              (const float*)Wv, (const float*)bv, alpha, nsum);
}

// ---------------- K7 body: output projection ----------------
template<typename T, typename OT>
__device__ void k7_body(const _Float16* nsum, const T* Wp, const T* bp, OT* out)
{
    int lane = threadIdx.x;
    float wp[64];
#pragma unroll
    for (int i = 0; i < 64; i++) wp[i] = cvt(Wp[i * 64 + lane]);
    float bpl = cvt(bp[lane]);
    const int ROWS = NN * 9;
    for (int r = blockIdx.x; r < ROWS; r += gridDim.x) {
        float xv = (float)nsum[(size_t)r * 64 + lane];
        float o0 = 0, o1 = 0, o2 = 0, o3 = 0;
#pragma unroll
        for (int i = 0; i < 64; i += 4) {
            o0 = fmaf(rlane(xv, i), wp[i], o0);
            o1 = fmaf(rlane(xv, i + 1), wp[i + 1], o1);
            o2 = fmaf(rlane(xv, i + 2), wp[i + 2], o2);
            o3 = fmaf(rlane(xv, i + 3), wp[i + 3], o3);
        }
        float o = o0 + o1 + o2 + o3;
        if ((r % 9) == 0) o += bpl;
        stOut(out, (size_t)r * 64 + lane, o);
    }
}

__global__ __launch_bounds__(64) void k7_proj(
    const _Float16* nsum, const void* Wp, const void* bp, void* out, const int* flag)
{
    if (*flag) k7_body<BF16, unsigned short>(nsum, (const BF16*)Wp, (const BF16*)bp, (unsigned short*)out);
    else       k7_body<float, float>(nsum, (const float*)Wp, (const float*)bp, (float*)out);
}

extern "C" void kernel_launch(void* const* d_in, const int* in_sizes, int n_in,
                              void* d_out, int out_size, void* d_ws, size_t ws_size,
                              hipStream_t stream) {
    const void* node_input = d_in[0];
    const void* edge_attr  = d_in[1];
    const void* edge_scal  = d_in[2];
    const void* W_src      = d_in[3];
    const void* b_src      = d_in[4];
    const void* W_dst      = d_in[5];
    const void* rad_W1     = d_in[6];
    const void* rad_b1     = d_in[7];
    const void* rad_ln_g   = d_in[8];
    const void* rad_ln_b   = d_in[9];
    const void* rad_W2     = d_in[10];
    const void* rad_off    = d_in[11];
    const void* W_alpha    = d_in[12];
    const void* b_alpha    = d_in[13];
    const void* alpha_dot  = d_in[14];
    const void* W_value    = d_in[15];
    const void* b_value    = d_in[16];
    const void* W_proj     = d_in[17];
    const void* b_proj     = d_in[18];
    const int* edge_src    = (const int*)d_in[19];
    const int* edge_dst    = (const int*)d_in[20];

    char* ws = (char*)d_ws;
    size_t ofs = 0;
    auto alloc = [&](size_t bytes) -> char* {
        char* r = ws + ofs;
        ofs = (ofs + bytes + 255) & ~(size_t)255;
        return r;
    };

    int* flag       = (int*)alloc(256);
    int* cnt        = (int*)alloc((size_t)NN * 4);
    int* offs       = (int*)alloc((size_t)(NN + 16) * 4);
    int* cur        = (int*)alloc((size_t)NN * 4);
    int* csr        = (int*)alloc((size_t)NE * 4);
    float* alpha    = (float*)alloc((size_t)NE * 8 * 4);      //  5.12 MB
    _Float16* fs    = (_Float16*)alloc((size_t)NN * 576 * 2); // 11.52 MB
    _Float16* fd    = (_Float16*)alloc((size_t)NN * 576 * 2); // 11.52 MB
    _Float16* hbuf  = (_Float16*)alloc((size_t)NE * 64 * 2);  // 20.48 MB
    _Float16* nsum  = (_Float16*)alloc((size_t)NN * 576 * 2); // 11.52 MB  -> total ~61 MB

    k0_zero<<<dim3((NE + 255) / 256), dim3(256), 0, stream>>>(cnt, csr, flag);
    kprobe<<<dim3(1), dim3(256), 0, stream>>>((const unsigned short*)node_input, flag);
    k1_feats<<<dim3(2048), dim3(64), 0, stream>>>(node_input, W_src, b_src, W_dst, fs, fd, flag);
    k2a_count<<<dim3(512), dim3(256), 0, stream>>>(edge_dst, cnt);
    k2b_scan<<<dim3(1), dim3(1024), 0, stream>>>(cnt, offs, cur);
    k2c_fill<<<dim3(512), dim3(256), 0, stream>>>(edge_dst, cur, csr);
    k3_h<<<dim3(4096), dim3(64), 0, stream>>>(edge_scal, rad_W1, rad_b1, rad_ln_g, rad_ln_b, hbuf, flag);
    k4_alpha<<<dim3(4096), dim3(64), 0, stream>>>(edge_attr, fs, fd, hbuf, rad_W2, rad_off,
                                                  W_alpha, b_alpha, alpha_dot,
                                                  edge_src, edge_dst, alpha, flag);
    k5_softmax<<<dim3((NN * 8 + 255) / 256), dim3(256), 0, stream>>>(offs, csr, alpha);
    k6_fused<<<dim3(10000), dim3(64), 0, stream>>>(offs, csr, edge_src, edge_attr, fs, fd, hbuf,
                                                   rad_W2, rad_off, W_value, b_value, alpha, nsum, flag);
    k7_proj<<<dim3(4096), dim3(64), 0, stream>>>(nsum, W_proj, b_proj, d_out, flag);
}

// Round 7
// 1483.572 us; speedup vs baseline: 4.5277x; 4.5277x over previous
//
#include <hip/hip_runtime.h>
#include <stdint.h>

#define NN 10000
#define NE 160000
// C=64, M=9, H=8, D=8, RH=64, WN=192

struct BF16 { unsigned short v; };

__device__ __forceinline__ float cvt(float x) { return x; }
__device__ __forceinline__ float cvt(BF16 x) {
    union { unsigned int i; float f; } u; u.i = ((unsigned int)x.v) << 16; return u.f;
}
__device__ __forceinline__ unsigned short f2b_us(float f) {
    union { float f; unsigned int i; } v; v.f = f;
    unsigned int x = v.i;
    unsigned int lsb = (x >> 16) & 1u;
    x += 0x7fffu + lsb;
    return (unsigned short)(x >> 16);
}
__device__ __forceinline__ float rlane(float v, int l) {
    return __uint_as_float((unsigned int)__builtin_amdgcn_readlane(__float_as_uint(v), l));
}
__device__ __forceinline__ float sigm(float x) { return 1.0f / (1.0f + __expf(-x)); }
__device__ __forceinline__ int clampi(int v, int hi) { return (unsigned)v >= (unsigned)hi ? 0 : v; }

// out-store helpers (dtype-dependent)
__device__ __forceinline__ void stOut(float* p, size_t i, float v) { p[i] = v; }
__device__ __forceinline__ void stOut(unsigned short* p, size_t i, float v) { p[i] = f2b_us(v); }

// ---------------- K0: zero cnt + csr, init flag ----------------
__global__ void k0_zero(int* __restrict__ cnt, int* __restrict__ csr, int* __restrict__ flag) {
    int i = blockIdx.x * blockDim.x + threadIdx.x;
    if (i == 0) *flag = 1;            // default: bf16; probe clears to 0 on f32 evidence
    if (i < NN) cnt[i] = 0;
    if (i < NE) csr[i] = 0;
}

// ---------------- KP: dtype probe ----------------
__global__ void kprobe(const unsigned short* __restrict__ x, int* __restrict__ flag) {
    int bad = 0;
    for (int i = threadIdx.x; i < 16384; i += blockDim.x) {
        unsigned e = (x[i] >> 7) & 0xFFu;
        bad += (e == 0xFFu);
    }
    if (bad > 0) atomicExch(flag, 0);  // f32 world
}

// ---------------- K1 body: node feats ----------------
template<typename T>
__device__ void k1_body(const T* x, const T* Ws, const T* bs, const T* Wd,
                        _Float16* fs, _Float16* fd)
{
    int lane = threadIdx.x;
    float ws[64], wd[64];
#pragma unroll
    for (int i = 0; i < 64; i++) { ws[i] = cvt(Ws[i * 64 + lane]); wd[i] = cvt(Wd[i * 64 + lane]); }
    float bsl = cvt(bs[lane]);
    const int ROWS = NN * 9;
    for (int r = blockIdx.x; r < ROWS; r += gridDim.x) {
        float xv = cvt(x[(size_t)r * 64 + lane]);
        float a0 = 0, a1 = 0, a2 = 0, a3 = 0, d0 = 0, d1 = 0, d2 = 0, d3 = 0;
#pragma unroll
        for (int i = 0; i < 64; i += 4) {
            float x0 = rlane(xv, i), x1 = rlane(xv, i + 1), x2 = rlane(xv, i + 2), x3 = rlane(xv, i + 3);
            a0 = fmaf(x0, ws[i], a0);     a1 = fmaf(x1, ws[i + 1], a1);
            a2 = fmaf(x2, ws[i + 2], a2); a3 = fmaf(x3, ws[i + 3], a3);
            d0 = fmaf(x0, wd[i], d0);     d1 = fmaf(x1, wd[i + 1], d1);
            d2 = fmaf(x2, wd[i + 2], d2); d3 = fmaf(x3, wd[i + 3], d3);
        }
        float as = a0 + a1 + a2 + a3;
        if ((r % 9) == 0) as += bsl;
        fs[(size_t)r * 64 + lane] = (_Float16)as;
        fd[(size_t)r * 64 + lane] = (_Float16)(d0 + d1 + d2 + d3);
    }
}

__global__ __launch_bounds__(64) void k1_feats(
    const void* x, const void* Ws, const void* bs, const void* Wd,
    _Float16* fs, _Float16* fd, const int* flag)
{
    if (*flag) k1_body((const BF16*)x, (const BF16*)Ws, (const BF16*)bs, (const BF16*)Wd, fs, fd);
    else       k1_body((const float*)x, (const float*)Ws, (const float*)bs, (const float*)Wd, fs, fd);
}

// ---------------- K2: CSR build ----------------
__global__ void k2a_count(const int* __restrict__ dst, int* __restrict__ cnt) {
    for (int e = blockIdx.x * blockDim.x + threadIdx.x; e < NE; e += gridDim.x * blockDim.x)
        atomicAdd(&cnt[clampi(dst[e], NN)], 1);
}

__global__ __launch_bounds__(1024) void k2b_scan(const int* __restrict__ cnt,
                                                 int* __restrict__ off, int* __restrict__ cur) {
    __shared__ int part[1024];
    int t = threadIdx.x;
    int base = t * 10;
    int loc[10]; int s = 0;
#pragma unroll
    for (int k = 0; k < 10; k++) { int i = base + k; int v = (i < NN) ? cnt[i] : 0; loc[k] = v; s += v; }
    part[t] = s; __syncthreads();
    for (int o = 1; o < 1024; o <<= 1) {
        int v = (t >= o) ? part[t - o] : 0;
        __syncthreads();
        part[t] += v;
        __syncthreads();
    }
    int run = (t == 0) ? 0 : part[t - 1];
#pragma unroll
    for (int k = 0; k < 10; k++) {
        int i = base + k;
        if (i < NN) { off[i] = run; cur[i] = run; run += loc[k]; }
    }
    if (t == 1023) off[NN] = part[1023];
}

__global__ void k2c_fill(const int* __restrict__ dst, int* __restrict__ cur, int* __restrict__ csr) {
    for (int e = blockIdx.x * blockDim.x + threadIdx.x; e < NE; e += gridDim.x * blockDim.x) {
        int d = clampi(dst[e], NN);
        int p = atomicAdd(&cur[d], 1);
        if ((unsigned)p < (unsigned)NE) csr[p] = e;
    }
}

// ---------------- K3 body: radial hidden h = silu(LN(s@W1+b1)*g+b) ----------------
template<typename T>
__device__ void k3_body(const T* es, const T* W1, const T* b1, const T* g, const T* bln,
                        _Float16* hout)
{
    int lane = threadIdx.x;
    float w1[64];
#pragma unroll
    for (int i = 0; i < 64; i++) w1[i] = cvt(W1[i * 64 + lane]);
    float b1l = cvt(b1[lane]), gl = cvt(g[lane]), bl = cvt(bln[lane]);
    for (int e = blockIdx.x; e < NE; e += gridDim.x) {
        float sv = cvt(es[(size_t)e * 64 + lane]);
        float h0 = 0, h1 = 0, h2 = 0, h3 = 0;
#pragma unroll
        for (int i = 0; i < 64; i += 4) {
            h0 = fmaf(rlane(sv, i), w1[i], h0);
            h1 = fmaf(rlane(sv, i + 1), w1[i + 1], h1);
            h2 = fmaf(rlane(sv, i + 2), w1[i + 2], h2);
            h3 = fmaf(rlane(sv, i + 3), w1[i + 3], h3);
        }
        float h = h0 + h1 + h2 + h3 + b1l;
        float s1 = h, s2 = h * h;
#pragma unroll
        for (int o = 32; o >= 1; o >>= 1) { s1 += __shfl_xor(s1, o, 64); s2 += __shfl_xor(s2, o, 64); }
        float mu = s1 * (1.0f / 64.0f);
        float var = fmaxf(s2 * (1.0f / 64.0f) - mu * mu, 0.0f);
        h = (h - mu) * rsqrtf(var + 1e-5f) * gl + bl;
        h = h * sigm(h);
        hout[(size_t)e * 64 + lane] = (_Float16)h;
    }
}

__global__ __launch_bounds__(64) void k3_h(
    const void* es, const void* W1, const void* b1, const void* g, const void* bln,
    _Float16* hout, const int* flag)
{
    if (*flag) k3_body((const BF16*)es, (const BF16*)W1, (const BF16*)b1, (const BF16*)g, (const BF16*)bln, hout);
    else       k3_body((const float*)es, (const float*)W1, (const float*)b1, (const float*)g, (const float*)bln, hout);
}

// ---------------- K3b body: wlc = h @ W2 + roff -> f16 [E][3][64] ----------------
template<typename T>
__device__ void k3b_body(const _Float16* hb, const T* W2, const T* roff, _Float16* wlc)
{
    int lane = threadIdx.x;
    float w2a[64], w2b[64], w2c[64];
#pragma unroll
    for (int i = 0; i < 64; i++) {
        w2a[i] = cvt(W2[i * 192 + lane]);
        w2b[i] = cvt(W2[i * 192 + 64 + lane]);
        w2c[i] = cvt(W2[i * 192 + 128 + lane]);
    }
    float o0 = cvt(roff[lane]), o1 = cvt(roff[64 + lane]), o2 = cvt(roff[128 + lane]);
    for (int e = blockIdx.x; e < NE; e += gridDim.x) {
        float hv = (float)hb[(size_t)e * 64 + lane];
        float wl0 = o0, wl1 = o1, wl2 = o2;
#pragma unroll
        for (int q = 0; q < 64; q++) {
            float hq = rlane(hv, q);
            wl0 = fmaf(hq, w2a[q], wl0);
            wl1 = fmaf(hq, w2b[q], wl1);
            wl2 = fmaf(hq, w2c[q], wl2);
        }
        size_t bo = (size_t)e * 192;
        wlc[bo + lane]       = (_Float16)wl0;
        wlc[bo + 64 + lane]  = (_Float16)wl1;
        wlc[bo + 128 + lane] = (_Float16)wl2;
    }
}

__global__ __launch_bounds__(64) void k3b_wlc(
    const _Float16* hb, const void* W2, const void* roff, _Float16* wlc, const int* flag)
{
    if (*flag) k3b_body(hb, (const BF16*)W2, (const BF16*)roff, wlc);
    else       k3b_body(hb, (const float*)W2, (const float*)roff, wlc);
}

// ---------------- K4 body: alpha logits (wlc precomputed) ----------------
template<typename T>
__device__ void k4_body(const T* ea, const _Float16* fs, const _Float16* fd,
                        const _Float16* wlc, const T* Wa, const T* ba, const T* adot,
                        const int* esrc, const int* edst, float* alpha)
{
    int lane = threadIdx.x;
    float wa[64];
#pragma unroll
    for (int i = 0; i < 64; i++) wa[i] = cvt(Wa[i * 64 + lane]);
    float bal = cvt(ba[lane]), adl = cvt(adot[lane]);
    for (int e = blockIdx.x; e < NE; e += gridDim.x) {
        int sn = clampi(esrc[e], NN), dn = clampi(edst[e], NN);
        float wl0 = (float)wlc[(size_t)e * 192 + lane];
        float ea0 = cvt(ea[(size_t)e * 9]);
        float m0 = ((float)fs[(size_t)sn * 576 + lane] + (float)fd[(size_t)dn * 576 + lane]) * ea0 * wl0;
        float a0 = 0, a1 = 0, a2 = 0, a3 = 0;
#pragma unroll
        for (int i = 0; i < 64; i += 4) {
            a0 = fmaf(rlane(m0, i), wa[i], a0);
            a1 = fmaf(rlane(m0, i + 1), wa[i + 1], a1);
            a2 = fmaf(rlane(m0, i + 2), wa[i + 2], a2);
            a3 = fmaf(rlane(m0, i + 3), wa[i + 3], a3);
        }
        float aw = a0 + a1 + a2 + a3 + bal;
        float f = aw * (0.2f + 0.8f * sigm(aw));   // smooth_lrelu
        float p = f * adl;
        p += __shfl_xor(p, 1, 64);
        p += __shfl_xor(p, 2, 64);
        p += __shfl_xor(p, 4, 64);
        if ((lane & 7) == 0) alpha[(size_t)e * 8 + (lane >> 3)] = p;
    }
}

__global__ __launch_bounds__(64) void k4_alpha(
    const void* ea, const _Float16* fs, const _Float16* fd, const _Float16* wlc,
    const void* Wa, const void* ba, const void* adot,
    const int* esrc, const int* edst, float* alpha, const int* flag)
{
    if (*flag) k4_body((const BF16*)ea, fs, fd, wlc, (const BF16*)Wa, (const BF16*)ba,
                       (const BF16*)adot, esrc, edst, alpha);
    else       k4_body((const float*)ea, fs, fd, wlc, (const float*)Wa, (const float*)ba,
                       (const float*)adot, esrc, edst, alpha);
}

// ---------------- K5: segment softmax per (node, head), in place ----------------
__global__ void k5_softmax(const int* __restrict__ off, const int* __restrict__ csr,
                           float* __restrict__ alpha) {
    int t = blockIdx.x * blockDim.x + threadIdx.x;
    if (t >= NN * 8) return;
    int n = t >> 3, h = t & 7;
    int b = off[n], en = off[n + 1];
    float mx = -3.4e38f;
    for (int i = b; i < en; i++)
        mx = fmaxf(mx, alpha[(size_t)clampi(csr[i], NE) * 8 + h]);
    float s = 0.f;
    for (int i = b; i < en; i++) {
        size_t ix = (size_t)clampi(csr[i], NE) * 8 + h;
        float ex = __expf(alpha[ix] - mx);
        s += ex;
        alpha[ix] = ex;
    }
    float inv = 1.0f / (s + 1e-16f);
    for (int i = b; i < en; i++) {
        size_t ix = (size_t)clampi(csr[i], NE) * 8 + h;
        alpha[ix] *= inv;
    }
}

// ---------------- K6 body: fused msg + value GEMV + gate + cp_tp + gather ----------------
// Register-resident: wv/wg (128) + msg[9]/cw[9]/acc[9]/fdv[9]. No LDS, no barriers.
template<typename T>
__device__ void k6_body(const int* off, const int* csr, const int* esrc,
                        const T* ea, const _Float16* fs, const _Float16* fd,
                        const _Float16* wlc, const T* Wv, const T* bv,
                        const float* alpha, _Float16* nsum)
{
    int lane = threadIdx.x;
    float wv[64], wg[64];
#pragma unroll
    for (int i = 0; i < 64; i++) {
        wv[i] = cvt(Wv[i * 128 + lane]);
        wg[i] = cvt(Wv[i * 128 + 64 + lane]);
    }
    float bvl = cvt(bv[lane]), bgl = cvt(bv[64 + lane]);
    for (int n = blockIdx.x; n < NN; n += gridDim.x) {
        float acc[9];
#pragma unroll
        for (int m = 0; m < 9; m++) acc[m] = 0.f;
        int b = off[n], en = off[n + 1];
        size_t db = (size_t)n * 576 + lane;
        float fdv[9];
#pragma unroll
        for (int m = 0; m < 9; m++) fdv[m] = (float)fd[db + m * 64];
        for (int i = b; i < en; i++) {
            int e = clampi(csr[i], NE);
            int sn = clampi(esrc[e], NN);
            size_t sb = (size_t)sn * 576 + lane;
            size_t wb = (size_t)e * 192;
            float wl0 = (float)wlc[wb + lane];
            float wl1 = (float)wlc[wb + 64 + lane];
            float wl2 = (float)wlc[wb + 128 + lane];
            float msg[9], cw[9];
#pragma unroll
            for (int m = 0; m < 9; m++) {
                float wl = (m == 0) ? wl0 : ((m < 4) ? wl1 : wl2);
                cw[m] = cvt(ea[(size_t)e * 9 + m]) * wl;
                msg[m] = ((float)fs[sb + m * 64] + fdv[m]) * cw[m];
            }
            float aw = alpha[(size_t)e * 8 + (lane >> 3)];
            // m=0 row: value + gate columns share the broadcast
            float va0 = 0, va1 = 0, ga0 = 0, ga1 = 0;
#pragma unroll
            for (int c = 0; c < 64; c += 2) {
                float bc0 = rlane(msg[0], c), bc1 = rlane(msg[0], c + 1);
                va0 = fmaf(bc0, wv[c], va0);     va1 = fmaf(bc1, wv[c + 1], va1);
                ga0 = fmaf(bc0, wg[c], ga0);     ga1 = fmaf(bc1, wg[c + 1], ga1);
            }
            float v0 = va0 + va1 + bvl;
            float gt = sigm(ga0 + ga1 + bgl);
            acc[0] = fmaf(v0 * sigm(v0) * cw[0], aw, acc[0]);
#pragma unroll
            for (int m = 1; m < 9; m++) {
                float q0 = 0, q1 = 0, q2 = 0, q3 = 0;
#pragma unroll
                for (int c = 0; c < 64; c += 4) {
                    q0 = fmaf(rlane(msg[m], c), wv[c], q0);
                    q1 = fmaf(rlane(msg[m], c + 1), wv[c + 1], q1);
                    q2 = fmaf(rlane(msg[m], c + 2), wv[c + 2], q2);
                    q3 = fmaf(rlane(msg[m], c + 3), wv[c + 3], q3);
                }
                acc[m] = fmaf((q0 + q1 + q2 + q3) * gt * cw[m], aw, acc[m]);
            }
        }
#pragma unroll
        for (int m = 0; m < 9; m++)
            nsum[(size_t)n * 576 + m * 64 + lane] = (_Float16)acc[m];
    }
}

__global__ __launch_bounds__(64) void k6_fused(
    const int* off, const int* csr, const int* esrc,
    const void* ea, const _Float16* fs, const _Float16* fd, const _Float16* wlc,
    const void* Wv, const void* bv,
    const float* alpha, _Float16* nsum, const int* flag)
{
    if (*flag) k6_body<BF16>(off, csr, esrc, (const BF16*)ea, fs, fd, wlc,
                             (const BF16*)Wv, (const BF16*)bv, alpha, nsum);
    else       k6_body<float>(off, csr, esrc, (const float*)ea, fs, fd, wlc,
                              (const float*)Wv, (const float*)bv, alpha, nsum);
}

// ---------------- K7 body: output projection ----------------
template<typename T, typename OT>
__device__ void k7_body(const _Float16* nsum, const T* Wp, const T* bp, OT* out)
{
    int lane = threadIdx.x;
    float wp[64];
#pragma unroll
    for (int i = 0; i < 64; i++) wp[i] = cvt(Wp[i * 64 + lane]);
    float bpl = cvt(bp[lane]);
    const int ROWS = NN * 9;
    for (int r = blockIdx.x; r < ROWS; r += gridDim.x) {
        float xv = (float)nsum[(size_t)r * 64 + lane];
        float o0 = 0, o1 = 0, o2 = 0, o3 = 0;
#pragma unroll
        for (int i = 0; i < 64; i += 4) {
            o0 = fmaf(rlane(xv, i), wp[i], o0);
            o1 = fmaf(rlane(xv, i + 1), wp[i + 1], o1);
            o2 = fmaf(rlane(xv, i + 2), wp[i + 2], o2);
            o3 = fmaf(rlane(xv, i + 3), wp[i + 3], o3);
        }
        float o = o0 + o1 + o2 + o3;
        if ((r % 9) == 0) o += bpl;
        stOut(out, (size_t)r * 64 + lane, o);
    }
}

__global__ __launch_bounds__(64) void k7_proj(
    const _Float16* nsum, const void* Wp, const void* bp, void* out, const int* flag)
{
    if (*flag) k7_body<BF16, unsigned short>(nsum, (const BF16*)Wp, (const BF16*)bp, (unsigned short*)out);
    else       k7_body<float, float>(nsum, (const float*)Wp, (const float*)bp, (float*)out);
}

extern "C" void kernel_launch(void* const* d_in, const int* in_sizes, int n_in,
                              void* d_out, int out_size, void* d_ws, size_t ws_size,
                              hipStream_t stream) {
    const void* node_input = d_in[0];
    const void* edge_attr  = d_in[1];
    const void* edge_scal  = d_in[2];
    const void* W_src      = d_in[3];
    const void* b_src      = d_in[4];
    const void* W_dst      = d_in[5];
    const void* rad_W1     = d_in[6];
    const void* rad_b1     = d_in[7];
    const void* rad_ln_g   = d_in[8];
    const void* rad_ln_b   = d_in[9];
    const void* rad_W2     = d_in[10];
    const void* rad_off    = d_in[11];
    const void* W_alpha    = d_in[12];
    const void* b_alpha    = d_in[13];
    const void* alpha_dot  = d_in[14];
    const void* W_value    = d_in[15];
    const void* b_value    = d_in[16];
    const void* W_proj     = d_in[17];
    const void* b_proj     = d_in[18];
    const int* edge_src    = (const int*)d_in[19];
    const int* edge_dst    = (const int*)d_in[20];

    char* ws = (char*)d_ws;
    size_t ofs = 0;
    auto alloc = [&](size_t bytes) -> char* {
        char* r = ws + ofs;
        ofs = (ofs + bytes + 255) & ~(size_t)255;
        return r;
    };

    int* flag       = (int*)alloc(256);
    int* cnt        = (int*)alloc((size_t)NN * 4);
    int* offs       = (int*)alloc((size_t)(NN + 16) * 4);
    int* cur        = (int*)alloc((size_t)NN * 4);
    int* csr        = (int*)alloc((size_t)NE * 4);
    float* alpha    = (float*)alloc((size_t)NE * 8 * 4);       //  5.12 MB
    _Float16* fs    = (_Float16*)alloc((size_t)NN * 576 * 2);  // 11.52 MB
    _Float16* fd    = (_Float16*)alloc((size_t)NN * 576 * 2);  // 11.52 MB
    _Float16* hbuf  = (_Float16*)alloc((size_t)NE * 64 * 2);   // 20.48 MB
    _Float16* wlc   = (_Float16*)alloc((size_t)NE * 192 * 2);  // 61.44 MB
    _Float16* nsum  = (_Float16*)alloc((size_t)NN * 576 * 2);  // 11.52 MB -> total ~122.4 MB

    k0_zero<<<dim3((NE + 255) / 256), dim3(256), 0, stream>>>(cnt, csr, flag);
    kprobe<<<dim3(1), dim3(256), 0, stream>>>((const unsigned short*)node_input, flag);
    k1_feats<<<dim3(2048), dim3(64), 0, stream>>>(node_input, W_src, b_src, W_dst, fs, fd, flag);
    k2a_count<<<dim3(512), dim3(256), 0, stream>>>(edge_dst, cnt);
    k2b_scan<<<dim3(1), dim3(1024), 0, stream>>>(cnt, offs, cur);
    k2c_fill<<<dim3(512), dim3(256), 0, stream>>>(edge_dst, cur, csr);
    k3_h<<<dim3(4096), dim3(64), 0, stream>>>(edge_scal, rad_W1, rad_b1, rad_ln_g, rad_ln_b, hbuf, flag);
    k3b_wlc<<<dim3(4096), dim3(64), 0, stream>>>(hbuf, rad_W2, rad_off, wlc, flag);
    k4_alpha<<<dim3(4096), dim3(64), 0, stream>>>(edge_attr, fs, fd, wlc, W_alpha, b_alpha,
                                                  alpha_dot, edge_src, edge_dst, alpha, flag);
    k5_softmax<<<dim3((NN * 8 + 255) / 256), dim3(256), 0, stream>>>(offs, csr, alpha);
    k6_fused<<<dim3(10000), dim3(64), 0, stream>>>(offs, csr, edge_src, edge_attr, fs, fd, wlc,
                                                   W_value, b_value, alpha, nsum, flag);
    k7_proj<<<dim3(4096), dim3(64), 0, stream>>>(nsum, W_proj, b_proj, d_out, flag);
}

// Round 8
// 820.419 us; speedup vs baseline: 8.1875x; 1.8083x over previous
//
#include <hip/hip_runtime.h>
#include <stdint.h>

#define NN 10000
#define NE 160000
// C=64, M=9, H=8, D=8, RH=64, WN=192

struct BF16 { unsigned short v; };
typedef _Float16 h2_t __attribute__((ext_vector_type(2)));

__device__ __forceinline__ float cvt(float x) { return x; }
__device__ __forceinline__ float cvt(BF16 x) {
    union { unsigned int i; float f; } u; u.i = ((unsigned int)x.v) << 16; return u.f;
}
__device__ __forceinline__ unsigned short f2b_us(float f) {
    union { float f; unsigned int i; } v; v.f = f;
    unsigned int x = v.i;
    unsigned int lsb = (x >> 16) & 1u;
    x += 0x7fffu + lsb;
    return (unsigned short)(x >> 16);
}
__device__ __forceinline__ float rlane(float v, int l) {
    return __uint_as_float((unsigned int)__builtin_amdgcn_readlane(__float_as_uint(v), l));
}
__device__ __forceinline__ h2_t rlane_pk(h2_t v, int l) {
    union { h2_t h; unsigned int u; } c; c.h = v;
    c.u = (unsigned int)__builtin_amdgcn_readlane(c.u, l);
    return c.h;
}
__device__ __forceinline__ h2_t pkh2(float a, float b) {
    h2_t r; r[0] = (_Float16)a; r[1] = (_Float16)b; return r;
}
__device__ __forceinline__ float fdot2f(h2_t a, h2_t b, float c) {
#if __has_builtin(__builtin_amdgcn_fdot2)
    return __builtin_amdgcn_fdot2(a, b, c, false);
#else
    return fmaf((float)a[0], (float)b[0], fmaf((float)a[1], (float)b[1], c));
#endif
}
__device__ __forceinline__ float sigm(float x) { return 1.0f / (1.0f + __expf(-x)); }
__device__ __forceinline__ int clampi(int v, int hi) { return (unsigned)v >= (unsigned)hi ? 0 : v; }

__device__ __forceinline__ void stOut(float* p, size_t i, float v) { p[i] = v; }
__device__ __forceinline__ void stOut(unsigned short* p, size_t i, float v) { p[i] = f2b_us(v); }

// ---------------- K0: zero cnt + csr, init flag ----------------
__global__ void k0_zero(int* __restrict__ cnt, int* __restrict__ csr, int* __restrict__ flag) {
    int i = blockIdx.x * blockDim.x + threadIdx.x;
    if (i == 0) *flag = 1;
    if (i < NN) cnt[i] = 0;
    if (i < NE) csr[i] = 0;
}

// ---------------- KP: dtype probe ----------------
__global__ void kprobe(const unsigned short* __restrict__ x, int* __restrict__ flag) {
    int bad = 0;
    for (int i = threadIdx.x; i < 16384; i += blockDim.x) {
        unsigned e = (x[i] >> 7) & 0xFFu;
        bad += (e == 0xFFu);
    }
    if (bad > 0) atomicExch(flag, 0);  // f32 world
}

// ---------------- K1: node feats ----------------
template<typename T>
__device__ void k1_body(const T* x, const T* Ws, const T* bs, const T* Wd,
                        _Float16* fs, _Float16* fd)
{
    int lane = threadIdx.x;
    float ws[64], wd[64];
#pragma unroll
    for (int i = 0; i < 64; i++) { ws[i] = cvt(Ws[i * 64 + lane]); wd[i] = cvt(Wd[i * 64 + lane]); }
    float bsl = cvt(bs[lane]);
    const int ROWS = NN * 9;
    for (int r = blockIdx.x; r < ROWS; r += gridDim.x) {
        float xv = cvt(x[(size_t)r * 64 + lane]);
        float a0 = 0, a1 = 0, a2 = 0, a3 = 0, d0 = 0, d1 = 0, d2 = 0, d3 = 0;
#pragma unroll
        for (int i = 0; i < 64; i += 4) {
            float x0 = rlane(xv, i), x1 = rlane(xv, i + 1), x2 = rlane(xv, i + 2), x3 = rlane(xv, i + 3);
            a0 = fmaf(x0, ws[i], a0);     a1 = fmaf(x1, ws[i + 1], a1);
            a2 = fmaf(x2, ws[i + 2], a2); a3 = fmaf(x3, ws[i + 3], a3);
            d0 = fmaf(x0, wd[i], d0);     d1 = fmaf(x1, wd[i + 1], d1);
            d2 = fmaf(x2, wd[i + 2], d2); d3 = fmaf(x3, wd[i + 3], d3);
        }
        float as = a0 + a1 + a2 + a3;
        if ((r % 9) == 0) as += bsl;
        fs[(size_t)r * 64 + lane] = (_Float16)as;
        fd[(size_t)r * 64 + lane] = (_Float16)(d0 + d1 + d2 + d3);
    }
}

__global__ __launch_bounds__(64) void k1_feats(
    const void* x, const void* Ws, const void* bs, const void* Wd,
    _Float16* fs, _Float16* fd, const int* flag)
{
    if (*flag) k1_body((const BF16*)x, (const BF16*)Ws, (const BF16*)bs, (const BF16*)Wd, fs, fd);
    else       k1_body((const float*)x, (const float*)Ws, (const float*)bs, (const float*)Wd, fs, fd);
}

// ---------------- K2: CSR build ----------------
__global__ void k2a_count(const int* __restrict__ dst, int* __restrict__ cnt) {
    for (int e = blockIdx.x * blockDim.x + threadIdx.x; e < NE; e += gridDim.x * blockDim.x)
        atomicAdd(&cnt[clampi(dst[e], NN)], 1);
}

__global__ __launch_bounds__(1024) void k2b_scan(const int* __restrict__ cnt,
                                                 int* __restrict__ off, int* __restrict__ cur) {
    __shared__ int part[1024];
    int t = threadIdx.x;
    int base = t * 10;
    int loc[10]; int s = 0;
#pragma unroll
    for (int k = 0; k < 10; k++) { int i = base + k; int v = (i < NN) ? cnt[i] : 0; loc[k] = v; s += v; }
    part[t] = s; __syncthreads();
    for (int o = 1; o < 1024; o <<= 1) {
        int v = (t >= o) ? part[t - o] : 0;
        __syncthreads();
        part[t] += v;
        __syncthreads();
    }
    int run = (t == 0) ? 0 : part[t - 1];
#pragma unroll
    for (int k = 0; k < 10; k++) {
        int i = base + k;
        if (i < NN) { off[i] = run; cur[i] = run; run += loc[k]; }
    }
    if (t == 1023) off[NN] = part[1023];
}

__global__ void k2c_fill(const int* __restrict__ dst, int* __restrict__ cur, int* __restrict__ csr) {
    for (int e = blockIdx.x * blockDim.x + threadIdx.x; e < NE; e += gridDim.x * blockDim.x) {
        int d = clampi(dst[e], NN);
        int p = atomicAdd(&cur[d], 1);
        if ((unsigned)p < (unsigned)NE) csr[p] = e;
    }
}

// ---------------- K3: fused radial MLP -> wlc f16 [E][3][64] ----------------
// h = silu(LN(s@W1+b1)*g+b); wlc = h@W2 + roff. pk-dot2 form.
template<typename T>
__device__ void k3_body(const T* es, const T* W1, const T* b1, const T* g, const T* bln,
                        const T* W2, const T* roff, _Float16* wlc)
{
    int lane = threadIdx.x;
    int j2 = (lane & 31) * 2;            // pair base channel
    h2_t w1p[32], w2ap[32], w2bp[32], w2cp[32];
#pragma unroll
    for (int i = 0; i < 32; i++) {
        w1p[i]  = pkh2(cvt(W1[(2 * i) * 64 + lane]),  cvt(W1[(2 * i + 1) * 64 + lane]));
        w2ap[i] = pkh2(cvt(W2[(2 * i) * 192 + lane]), cvt(W2[(2 * i + 1) * 192 + lane]));
        w2bp[i] = pkh2(cvt(W2[(2 * i) * 192 + 64 + lane]), cvt(W2[(2 * i + 1) * 192 + 64 + lane]));
        w2cp[i] = pkh2(cvt(W2[(2 * i) * 192 + 128 + lane]), cvt(W2[(2 * i + 1) * 192 + 128 + lane]));
    }
    float b1l = cvt(b1[lane]), gl = cvt(g[lane]), bl = cvt(bln[lane]);
    float o0 = cvt(roff[lane]), o1 = cvt(roff[64 + lane]), o2 = cvt(roff[128 + lane]);
    for (int e = blockIdx.x; e < NE; e += gridDim.x) {
        // s pairs (dup across halves)
        h2_t esp = pkh2(cvt(es[(size_t)e * 64 + j2]), cvt(es[(size_t)e * 64 + j2 + 1]));
        float h0 = b1l, h1 = 0, h2v = 0, h3 = 0;
#pragma unroll
        for (int i = 0; i < 32; i += 4) {
            h0 = fdot2f(rlane_pk(esp, i),     w1p[i],     h0);
            h1 = fdot2f(rlane_pk(esp, i + 1), w1p[i + 1], h1);
            h2v = fdot2f(rlane_pk(esp, i + 2), w1p[i + 2], h2v);
            h3 = fdot2f(rlane_pk(esp, i + 3), w1p[i + 3], h3);
        }
        float h = h0 + h1 + h2v + h3;
        float s1 = h, s2 = h * h;
#pragma unroll
        for (int o = 32; o >= 1; o >>= 1) { s1 += __shfl_xor(s1, o, 64); s2 += __shfl_xor(s2, o, 64); }
        float mu = s1 * (1.0f / 64.0f);
        float var = fmaxf(s2 * (1.0f / 64.0f) - mu * mu, 0.0f);
        h = (h - mu) * rsqrtf(var + 1e-5f) * gl + bl;
        h = h * sigm(h);
        // pack h pairs: lane holds (h[2j], h[2j+1])
        h2_t hp = pkh2(__shfl(h, j2, 64), __shfl(h, j2 + 1, 64));
        float a0 = o0, a1 = 0, b0 = o1, b1v = 0, c0 = o2, c1 = 0;
#pragma unroll
        for (int i = 0; i < 32; i += 2) {
            h2_t bc0 = rlane_pk(hp, i), bc1 = rlane_pk(hp, i + 1);
            a0 = fdot2f(bc0, w2ap[i], a0);     a1 = fdot2f(bc1, w2ap[i + 1], a1);
            b0 = fdot2f(bc0, w2bp[i], b0);     b1v = fdot2f(bc1, w2bp[i + 1], b1v);
            c0 = fdot2f(bc0, w2cp[i], c0);     c1 = fdot2f(bc1, w2cp[i + 1], c1);
        }
        size_t bo = (size_t)e * 192;
        wlc[bo + lane]       = (_Float16)(a0 + a1);
        wlc[bo + 64 + lane]  = (_Float16)(b0 + b1v);
        wlc[bo + 128 + lane] = (_Float16)(c0 + c1);
    }
}

__global__ __launch_bounds__(64) void k3_wlc(
    const void* es, const void* W1, const void* b1, const void* g, const void* bln,
    const void* W2, const void* roff, _Float16* wlc, const int* flag)
{
    if (*flag) k3_body((const BF16*)es, (const BF16*)W1, (const BF16*)b1, (const BF16*)g,
                       (const BF16*)bln, (const BF16*)W2, (const BF16*)roff, wlc);
    else       k3_body((const float*)es, (const float*)W1, (const float*)b1, (const float*)g,
                       (const float*)bln, (const float*)W2, (const float*)roff, wlc);
}

// ---------------- K4: alpha logits (pk-dot2) ----------------
template<typename T>
__device__ void k4_body(const T* ea, const _Float16* fs, const _Float16* fd,
                        const _Float16* wlc, const T* Wa, const T* ba, const T* adot,
                        const int* esrc, const int* edst, float* alpha)
{
    int lane = threadIdx.x;
    int j2 = (lane & 31) * 2;
    h2_t wap[32];
#pragma unroll
    for (int i = 0; i < 32; i++)
        wap[i] = pkh2(cvt(Wa[(2 * i) * 64 + lane]), cvt(Wa[(2 * i + 1) * 64 + lane]));
    float bal = cvt(ba[lane]), adl = cvt(adot[lane]);
    for (int e = blockIdx.x; e < NE; e += gridDim.x) {
        int sn = clampi(esrc[e], NN), dn = clampi(edst[e], NN);
        h2_t fsp = *(const h2_t*)&fs[(size_t)sn * 576 + j2];
        h2_t fdp = *(const h2_t*)&fd[(size_t)dn * 576 + j2];
        h2_t wlp = *(const h2_t*)&wlc[(size_t)e * 192 + j2];
        float ea0 = cvt(ea[(size_t)e * 9]);
        float m0a = ((float)fsp[0] + (float)fdp[0]) * ea0 * (float)wlp[0];
        float m0b = ((float)fsp[1] + (float)fdp[1]) * ea0 * (float)wlp[1];
        h2_t m0p = pkh2(m0a, m0b);
        float a0 = bal, a1 = 0, a2 = 0, a3 = 0;
#pragma unroll
        for (int i = 0; i < 32; i += 4) {
            a0 = fdot2f(rlane_pk(m0p, i),     wap[i],     a0);
            a1 = fdot2f(rlane_pk(m0p, i + 1), wap[i + 1], a1);
            a2 = fdot2f(rlane_pk(m0p, i + 2), wap[i + 2], a2);
            a3 = fdot2f(rlane_pk(m0p, i + 3), wap[i + 3], a3);
        }
        float aw = a0 + a1 + a2 + a3;
        float f = aw * (0.2f + 0.8f * sigm(aw));   // smooth_lrelu
        float p = f * adl;
        p += __shfl_xor(p, 1, 64);
        p += __shfl_xor(p, 2, 64);
        p += __shfl_xor(p, 4, 64);
        if ((lane & 7) == 0) alpha[(size_t)e * 8 + (lane >> 3)] = p;
    }
}

__global__ __launch_bounds__(64) void k4_alpha(
    const void* ea, const _Float16* fs, const _Float16* fd, const _Float16* wlc,
    const void* Wa, const void* ba, const void* adot,
    const int* esrc, const int* edst, float* alpha, const int* flag)
{
    if (*flag) k4_body((const BF16*)ea, fs, fd, wlc, (const BF16*)Wa, (const BF16*)ba,
                       (const BF16*)adot, esrc, edst, alpha);
    else       k4_body((const float*)ea, fs, fd, wlc, (const float*)Wa, (const float*)ba,
                       (const float*)adot, esrc, edst, alpha);
}

// ---------------- K5: segment softmax per (node, head), in place ----------------
__global__ void k5_softmax(const int* __restrict__ off, const int* __restrict__ csr,
                           float* __restrict__ alpha) {
    int t = blockIdx.x * blockDim.x + threadIdx.x;
    if (t >= NN * 8) return;
    int n = t >> 3, h = t & 7;
    int b = off[n], en = off[n + 1];
    float mx = -3.4e38f;
    for (int i = b; i < en; i++)
        mx = fmaxf(mx, alpha[(size_t)clampi(csr[i], NE) * 8 + h]);
    float s = 0.f;
    for (int i = b; i < en; i++) {
        size_t ix = (size_t)clampi(csr[i], NE) * 8 + h;
        float ex = __expf(alpha[ix] - mx);
        s += ex;
        alpha[ix] = ex;
    }
    float inv = 1.0f / (s + 1e-16f);
    for (int i = b; i < en; i++) {
        size_t ix = (size_t)clampi(csr[i], NE) * 8 + h;
        alpha[ix] *= inv;
    }
}

// ---------------- K6: fused msg + value GEMV (pk-dot2) + gate + cp_tp + gather ----------------
template<typename T>
__device__ void k6_body(const int* off, const int* csr, const int* esrc,
                        const T* ea, const _Float16* fs, const _Float16* fd,
                        const _Float16* wlc, const T* Wv, const T* bv,
                        const float* alpha, _Float16* nsum)
{
    int lane = threadIdx.x;
    int j2 = (lane & 31) * 2;
    h2_t wvp[32], wgp[32];
#pragma unroll
    for (int i = 0; i < 32; i++) {
        wvp[i] = pkh2(cvt(Wv[(2 * i) * 128 + lane]), cvt(Wv[(2 * i + 1) * 128 + lane]));
        wgp[i] = pkh2(cvt(Wv[(2 * i) * 128 + 64 + lane]), cvt(Wv[(2 * i + 1) * 128 + 64 + lane]));
    }
    float bvl = cvt(bv[lane]), bgl = cvt(bv[64 + lane]);
    for (int n = blockIdx.x; n < NN; n += gridDim.x) {
        float acc[9];
#pragma unroll
        for (int m = 0; m < 9; m++) acc[m] = 0.f;
        int b = off[n], en = off[n + 1];
        size_t db2 = (size_t)n * 576 + j2;
        h2_t fdp[9];
#pragma unroll
        for (int m = 0; m < 9; m++) fdp[m] = *(const h2_t*)&fd[db2 + m * 64];
        for (int i = b; i < en; i++) {
            int e = clampi(csr[i], NE);
            int sn = clampi(esrc[e], NN);
            size_t sb2 = (size_t)sn * 576 + j2;
            size_t wb = (size_t)e * 192;
            // wl pairs (for msg build) and per-lane scalars (for epilogue cp_tp)
            h2_t wl0p = *(const h2_t*)&wlc[wb + j2];
            h2_t wl1p = *(const h2_t*)&wlc[wb + 64 + j2];
            h2_t wl2p = *(const h2_t*)&wlc[wb + 128 + j2];
            float wl0s = (float)wlc[wb + lane];
            float wl1s = (float)wlc[wb + 64 + lane];
            float wl2s = (float)wlc[wb + 128 + lane];
            float aw = alpha[(size_t)e * 8 + (lane >> 3)];
            h2_t msgp[9];
            float cws[9];
#pragma unroll
            for (int m = 0; m < 9; m++) {
                float eam = cvt(ea[(size_t)e * 9 + m]);
                h2_t wlp = (m == 0) ? wl0p : ((m < 4) ? wl1p : wl2p);
                float wls = (m == 0) ? wl0s : ((m < 4) ? wl1s : wl2s);
                cws[m] = eam * wls;
                h2_t fsp = *(const h2_t*)&fs[sb2 + m * 64];
                float ma = ((float)fsp[0] + (float)fdp[m][0]) * eam * (float)wlp[0];
                float mb = ((float)fsp[1] + (float)fdp[m][1]) * eam * (float)wlp[1];
                msgp[m] = pkh2(ma, mb);
            }
            // m=0: value + gate dots share broadcasts
            float va0 = bvl, va1 = 0, ga0 = bgl, ga1 = 0;
#pragma unroll
            for (int c = 0; c < 32; c += 2) {
                h2_t bc0 = rlane_pk(msgp[0], c), bc1 = rlane_pk(msgp[0], c + 1);
                va0 = fdot2f(bc0, wvp[c], va0);     va1 = fdot2f(bc1, wvp[c + 1], va1);
                ga0 = fdot2f(bc0, wgp[c], ga0);     ga1 = fdot2f(bc1, wgp[c + 1], ga1);
            }
            float v0 = va0 + va1;
            float gt = sigm(ga0 + ga1);
            acc[0] = fmaf(v0 * sigm(v0) * cws[0], aw, acc[0]);
#pragma unroll
            for (int m = 1; m < 9; m++) {
                float q0 = 0, q1 = 0, q2 = 0, q3 = 0;
#pragma unroll
                for (int c = 0; c < 32; c += 4) {
                    q0 = fdot2f(rlane_pk(msgp[m], c),     wvp[c],     q0);
                    q1 = fdot2f(rlane_pk(msgp[m], c + 1), wvp[c + 1], q1);
                    q2 = fdot2f(rlane_pk(msgp[m], c + 2), wvp[c + 2], q2);
                    q3 = fdot2f(rlane_pk(msgp[m], c + 3), wvp[c + 3], q3);
                }
                acc[m] = fmaf((q0 + q1 + q2 + q3) * gt * cws[m], aw, acc[m]);
            }
        }
#pragma unroll
        for (int m = 0; m < 9; m++)
            nsum[(size_t)n * 576 + m * 64 + lane] = (_Float16)acc[m];
    }
}

__global__ __launch_bounds__(64) void k6_fused(
    const int* off, const int* csr, const int* esrc,
    const void* ea, const _Float16* fs, const _Float16* fd, const _Float16* wlc,
    const void* Wv, const void* bv,
    const float* alpha, _Float16* nsum, const int* flag)
{
    if (*flag) k6_body<BF16>(off, csr, esrc, (const BF16*)ea, fs, fd, wlc,
                             (const BF16*)Wv, (const BF16*)bv, alpha, nsum);
    else       k6_body<float>(off, csr, esrc, (const float*)ea, fs, fd, wlc,
                              (const float*)Wv, (const float*)bv, alpha, nsum);
}

// ---------------- K7: output projection ----------------
template<typename T, typename OT>
__device__ void k7_body(const _Float16* nsum, const T* Wp, const T* bp, OT* out)
{
    int lane = threadIdx.x;
    float wp[64];
#pragma unroll
    for (int i = 0; i < 64; i++) wp[i] = cvt(Wp[i * 64 + lane]);
    float bpl = cvt(bp[lane]);
    const int ROWS = NN * 9;
    for (int r = blockIdx.x; r < ROWS; r += gridDim.x) {
        float xv = (float)nsum[(size_t)r * 64 + lane];
        float o0 = 0, o1 = 0, o2 = 0, o3 = 0;
#pragma unroll
        for (int i = 0; i < 64; i += 4) {
            o0 = fmaf(rlane(xv, i), wp[i], o0);
            o1 = fmaf(rlane(xv, i + 1), wp[i + 1], o1);
            o2 = fmaf(rlane(xv, i + 2), wp[i + 2], o2);
            o3 = fmaf(rlane(xv, i + 3), wp[i + 3], o3);
        }
        float o = o0 + o1 + o2 + o3;
        if ((r % 9) == 0) o += bpl;
        stOut(out, (size_t)r * 64 + lane, o);
    }
}

__global__ __launch_bounds__(64) void k7_proj(
    const _Float16* nsum, const void* Wp, const void* bp, void* out, const int* flag)
{
    if (*flag) k7_body<BF16, unsigned short>(nsum, (const BF16*)Wp, (const BF16*)bp, (unsigned short*)out);
    else       k7_body<float, float>(nsum, (const float*)Wp, (const float*)bp, (float*)out);
}

extern "C" void kernel_launch(void* const* d_in, const int* in_sizes, int n_in,
                              void* d_out, int out_size, void* d_ws, size_t ws_size,
                              hipStream_t stream) {
    const void* node_input = d_in[0];
    const void* edge_attr  = d_in[1];
    const void* edge_scal  = d_in[2];
    const void* W_src      = d_in[3];
    const void* b_src      = d_in[4];
    const void* W_dst      = d_in[5];
    const void* rad_W1     = d_in[6];
    const void* rad_b1     = d_in[7];
    const void* rad_ln_g   = d_in[8];
    const void* rad_ln_b   = d_in[9];
    const void* rad_W2     = d_in[10];
    const void* rad_off    = d_in[11];
    const void* W_alpha    = d_in[12];
    const void* b_alpha    = d_in[13];
    const void* alpha_dot  = d_in[14];
    const void* W_value    = d_in[15];
    const void* b_value    = d_in[16];
    const void* W_proj     = d_in[17];
    const void* b_proj     = d_in[18];
    const int* edge_src    = (const int*)d_in[19];
    const int* edge_dst    = (const int*)d_in[20];

    char* ws = (char*)d_ws;
    size_t ofs = 0;
    auto alloc = [&](size_t bytes) -> char* {
        char* r = ws + ofs;
        ofs = (ofs + bytes + 255) & ~(size_t)255;
        return r;
    };

    int* flag       = (int*)alloc(256);
    int* cnt        = (int*)alloc((size_t)NN * 4);
    int* offs       = (int*)alloc((size_t)(NN + 16) * 4);
    int* cur        = (int*)alloc((size_t)NN * 4);
    int* csr        = (int*)alloc((size_t)NE * 4);
    float* alpha    = (float*)alloc((size_t)NE * 8 * 4);       //  5.12 MB
    _Float16* fs    = (_Float16*)alloc((size_t)NN * 576 * 2);  // 11.52 MB
    _Float16* fd    = (_Float16*)alloc((size_t)NN * 576 * 2);  // 11.52 MB
    _Float16* wlc   = (_Float16*)alloc((size_t)NE * 192 * 2);  // 61.44 MB
    _Float16* nsum  = (_Float16*)alloc((size_t)NN * 576 * 2);  // 11.52 MB -> total ~102 MB

    k0_zero<<<dim3((NE + 255) / 256), dim3(256), 0, stream>>>(cnt, csr, flag);
    kprobe<<<dim3(1), dim3(256), 0, stream>>>((const unsigned short*)node_input, flag);
    k1_feats<<<dim3(2048), dim3(64), 0, stream>>>(node_input, W_src, b_src, W_dst, fs, fd, flag);
    k2a_count<<<dim3(512), dim3(256), 0, stream>>>(edge_dst, cnt);
    k2b_scan<<<dim3(1), dim3(1024), 0, stream>>>(cnt, offs, cur);
    k2c_fill<<<dim3(512), dim3(256), 0, stream>>>(edge_dst, cur, csr);
    k3_wlc<<<dim3(4096), dim3(64), 0, stream>>>(edge_scal, rad_W1, rad_b1, rad_ln_g, rad_ln_b,
                                                rad_W2, rad_off, wlc, flag);
    k4_alpha<<<dim3(4096), dim3(64), 0, stream>>>(edge_attr, fs, fd, wlc, W_alpha, b_alpha,
                                                  alpha_dot, edge_src, edge_dst, alpha, flag);
    k5_softmax<<<dim3((NN * 8 + 255) / 256), dim3(256), 0, stream>>>(offs, csr, alpha);
    k6_fused<<<dim3(10000), dim3(64), 0, stream>>>(offs, csr, edge_src, edge_attr, fs, fd, wlc,
                                                   W_value, b_value, alpha, nsum, flag);
    k7_proj<<<dim3(4096), dim3(64), 0, stream>>>(nsum, W_proj, b_proj, d_out, flag);
}